// Round 7
// baseline (203.988 us; speedup 1.0000x reference)
//
#include <hip/hip_runtime.h>

// DPQ network:
//  phase A: response argmax via split-bf16 MFMA (ah*bh + al*bh + ah*bl) with
//           certification margin; exact f32 dot for the winner (neg_mse)
//  phase B: exact f32 rescue for uncertified (b,c) entries (first-index tie)
//  k_gemm:  codebook-gather GEMM (bf16 MFMA), unchanged from passing rounds
// B=32768, C=32, K=256, D_SUB=16, D_IN=512, D_OUT=512

#define NB 32768
#define NC 32
#define NK 256
#define NDS 16
#define NDIN 512
#define NDOUT 512
#define CERT 0.05f

typedef __attribute__((ext_vector_type(8))) short s8v;   // 8 bf16 in 4 VGPRs
typedef __attribute__((ext_vector_type(4))) float f4v;   // MFMA accumulator

__device__ __forceinline__ unsigned short f2bf(float f) {
  unsigned int u = __float_as_uint(f);
  u += 0x7fffu + ((u >> 16) & 1u);   // RNE
  return (unsigned short)(u >> 16);
}
__device__ __forceinline__ float bf2f(unsigned short h) {
  return __uint_as_float(((unsigned int)h) << 16);
}

__device__ __forceinline__ void gload16(const void* g, void* l) {
  __builtin_amdgcn_global_load_lds(
      (const __attribute__((address_space(1))) void*)g,
      (__attribute__((address_space(3))) void*)l, 16, 0, 0);
}

// exact f32 dot over 16 dims, sequential fold (same association everywhere)
__device__ __forceinline__ float dot16(const float* x, const float* cj) {
  float4 a0 = *(const float4*)(x + 0),  a1 = *(const float4*)(x + 4);
  float4 a2 = *(const float4*)(x + 8),  a3 = *(const float4*)(x + 12);
  float4 c0 = *(const float4*)(cj + 0), c1 = *(const float4*)(cj + 4);
  float4 c2 = *(const float4*)(cj + 8), c3 = *(const float4*)(cj + 12);
  float s = a0.x * c0.x;
  s = fmaf(a0.y, c0.y, s); s = fmaf(a0.z, c0.z, s); s = fmaf(a0.w, c0.w, s);
  s = fmaf(a1.x, c1.x, s); s = fmaf(a1.y, c1.y, s); s = fmaf(a1.z, c1.z, s); s = fmaf(a1.w, c1.w, s);
  s = fmaf(a2.x, c2.x, s); s = fmaf(a2.y, c2.y, s); s = fmaf(a2.z, c2.z, s); s = fmaf(a2.w, c2.w, s);
  s = fmaf(a3.x, c3.x, s); s = fmaf(a3.y, c3.y, s); s = fmaf(a3.z, c3.z, s); s = fmaf(a3.w, c3.w, s);
  return s;
}

// ---------------------------------------------------------------------------
// Kernel 0: Wt[n][k] = bf16(W[k][n]); centsH/centsL = bf16 hi/lo split of cents
// ---------------------------------------------------------------------------
__global__ __launch_bounds__(256) void k_prep(const float* __restrict__ W,
                                              const float* __restrict__ cents,
                                              unsigned short* __restrict__ Wt,
                                              unsigned short* __restrict__ centsH,
                                              unsigned short* __restrict__ centsL) {
  const int t = threadIdx.x;
  const int bid = blockIdx.x;
  if (bid < 256) {
    __shared__ float tile[32][33];
    const int k0 = (bid >> 4) << 5;
    const int n0 = (bid & 15) << 5;
    const int tx = t & 31, ty = t >> 5;
#pragma unroll
    for (int i = 0; i < 4; ++i) {
      int r = ty + i * 8;
      tile[r][tx] = W[(size_t)(k0 + r) * NDOUT + n0 + tx];
    }
    __syncthreads();
#pragma unroll
    for (int i = 0; i < 4; ++i) {
      int r = ty + i * 8;
      Wt[(size_t)(n0 + r) * NDIN + k0 + tx] = f2bf(tile[tx][r]);
    }
  } else {
    // hi/lo split of centroids: 131072 floats, blocks 256..287
    const int i0 = (bid - 256) * 4096 + t * 16;
#pragma unroll
    for (int j = 0; j < 4; ++j) {
      float4 v = *(const float4*)(cents + i0 + j * 4);
      unsigned short h0 = f2bf(v.x), h1 = f2bf(v.y), h2 = f2bf(v.z), h3 = f2bf(v.w);
      unsigned short l0 = f2bf(v.x - bf2f(h0)), l1 = f2bf(v.y - bf2f(h1));
      unsigned short l2 = f2bf(v.z - bf2f(h2)), l3 = f2bf(v.w - bf2f(h3));
      *(ushort4*)(centsH + i0 + j * 4) = make_ushort4(h0, h1, h2, h3);
      *(ushort4*)(centsL + i0 + j * 4) = make_ushort4(l0, l1, l2, l3);
    }
  }
}

// ---------------------------------------------------------------------------
// Phase A: per wave = 32 b's x 1 c. resp^T tile via MFMA:
//   A (M=16 k-rows, K=32) = [cent_hi | cent_lo], B (K=32, N=16 b-cols):
//   pass1 B=[bh|bh] -> ah*bh + al*bh ; pass2 B=[bl|0] -> + ah*bl
// Track (best, second, bestk) per score-lane; butterfly over lane groups;
// certify gap > CERT; exact f32 dot for winner -> neg_mse.
// ---------------------------------------------------------------------------
__global__ __launch_bounds__(256) void k_phaseA(const float* __restrict__ inputs,
                                                const unsigned short* __restrict__ centsH,
                                                const unsigned short* __restrict__ centsL,
                                                const float* __restrict__ cents,
                                                float* __restrict__ negout,
                                                float* __restrict__ codefout,
                                                int* __restrict__ codeint,
                                                unsigned char* __restrict__ flags) {
  const int t = threadIdx.x;
  const int l = t & 63;
  const int w = t >> 6;
  const int c = blockIdx.y;
  const int b0 = blockIdx.x * 128 + w * 32;   // this wave: b0..b0+31 (two 16-col subtiles)
  const int g = l >> 4;
  const int col = l & 15;
  const int dh = (g & 1) * 8;                 // d-range this lane covers (contraction slots)
  const int g4 = g * 4;                       // k-row offset of this lane's C rows

  // ---- B fragments (two subtiles), hi/lo split in-register
  s8v bh0, bl0, bh1, bl1;
  {
    const float* r0 = inputs + ((size_t)(b0 + col) * NC + c) * NDS + dh;
    const float* r1 = inputs + ((size_t)(b0 + 16 + col) * NC + c) * NDS + dh;
    float4 u0 = *(const float4*)(r0), u1 = *(const float4*)(r0 + 4);
    float4 v0 = *(const float4*)(r1), v1 = *(const float4*)(r1 + 4);
    unsigned short h0 = f2bf(u0.x), h1 = f2bf(u0.y), h2 = f2bf(u0.z), h3 = f2bf(u0.w);
    unsigned short h4 = f2bf(u1.x), h5 = f2bf(u1.y), h6 = f2bf(u1.z), h7 = f2bf(u1.w);
    bh0 = s8v{(short)h0, (short)h1, (short)h2, (short)h3,
              (short)h4, (short)h5, (short)h6, (short)h7};
    bl0 = s8v{(short)f2bf(u0.x - bf2f(h0)), (short)f2bf(u0.y - bf2f(h1)),
              (short)f2bf(u0.z - bf2f(h2)), (short)f2bf(u0.w - bf2f(h3)),
              (short)f2bf(u1.x - bf2f(h4)), (short)f2bf(u1.y - bf2f(h5)),
              (short)f2bf(u1.z - bf2f(h6)), (short)f2bf(u1.w - bf2f(h7))};
    unsigned short j0 = f2bf(v0.x), j1 = f2bf(v0.y), j2 = f2bf(v0.z), j3 = f2bf(v0.w);
    unsigned short j4 = f2bf(v1.x), j5 = f2bf(v1.y), j6 = f2bf(v1.z), j7 = f2bf(v1.w);
    bh1 = s8v{(short)j0, (short)j1, (short)j2, (short)j3,
              (short)j4, (short)j5, (short)j6, (short)j7};
    bl1 = s8v{(short)f2bf(v0.x - bf2f(j0)), (short)f2bf(v0.y - bf2f(j1)),
              (short)f2bf(v0.z - bf2f(j2)), (short)f2bf(v0.w - bf2f(j3)),
              (short)f2bf(v1.x - bf2f(j4)), (short)f2bf(v1.y - bf2f(j5)),
              (short)f2bf(v1.z - bf2f(j6)), (short)f2bf(v1.w - bf2f(j7))};
    const s8v zer = {0, 0, 0, 0, 0, 0, 0, 0};
    if (l >= 32) { bl0 = zer; bl1 = zer; }    // kappa>=16 of pass-2 B is zero
  }

  // A-operand base: lanes g0,g1 -> hi; g2,g3 -> lo (kappa 16..31 = al)
  const unsigned short* ab =
      (l < 32 ? centsH : centsL) + ((size_t)c * NK + col) * NDS + dh;

  float best0 = -3.0e38f, sec0 = -3.0e38f;
  float best1 = -3.0e38f, sec1 = -3.0e38f;
  int bk0 = 0, bk1 = 0;
  const f4v zz = {0.0f, 0.0f, 0.0f, 0.0f};

#pragma unroll
  for (int kt = 0; kt < 16; ++kt) {
    s8v a = *(const s8v*)(ab + kt * 256);     // 16 k-rows per tile, 16 elems/row
    f4v acc0 = __builtin_amdgcn_mfma_f32_16x16x32_bf16(a, bh0, zz, 0, 0, 0);
    acc0 = __builtin_amdgcn_mfma_f32_16x16x32_bf16(a, bl0, acc0, 0, 0, 0);
    f4v acc1 = __builtin_amdgcn_mfma_f32_16x16x32_bf16(a, bh1, zz, 0, 0, 0);
    acc1 = __builtin_amdgcn_mfma_f32_16x16x32_bf16(a, bl1, acc1, 0, 0, 0);
#pragma unroll
    for (int r = 0; r < 4; ++r) {
      const int kc = kt * 16 + r;             // + g4 folded at the end
      float v = acc0[r];
      float mn = fminf(v, best0);
      sec0 = fmaxf(sec0, mn);
      bool gt = v > best0;
      bk0 = gt ? kc : bk0;
      best0 = fmaxf(best0, v);
      v = acc1[r];
      mn = fminf(v, best1);
      sec1 = fmaxf(sec1, mn);
      gt = v > best1;
      bk1 = gt ? kc : bk1;
      best1 = fmaxf(best1, v);
    }
  }
  bk0 += g4;
  bk1 += g4;

  // butterfly across the 4 lane-groups (same b-col at l, l^16, l^32, l^48)
#pragma unroll
  for (int off = 16; off <= 32; off <<= 1) {
    float vb = __shfl_xor(best0, off);
    float sb = __shfl_xor(sec0, off);
    int kb = __shfl_xor(bk0, off);
    float mn = fminf(best0, vb);
    sec0 = fmaxf(fmaxf(sec0, sb), mn);
    bool take = (vb > best0) || (vb == best0 && kb < bk0);
    bk0 = take ? kb : bk0;
    best0 = fmaxf(best0, vb);

    vb = __shfl_xor(best1, off);
    sb = __shfl_xor(sec1, off);
    kb = __shfl_xor(bk1, off);
    mn = fminf(best1, vb);
    sec1 = fmaxf(fmaxf(sec1, sb), mn);
    take = (vb > best1) || (vb == best1 && kb < bk1);
    bk1 = take ? kb : bk1;
    best1 = fmaxf(best1, vb);
  }

  // lanes 0..31 finalize b = b0 + l (sub = l>>4 picks the subtile result)
  if (l < 32) {
    const int sub = l >> 4;
    float best = sub ? best1 : best0;
    float sec = sub ? sec1 : sec0;
    int bk = sub ? bk1 : bk0;
    const int b = b0 + l;
    const float* xr = inputs + ((size_t)b * NC + c) * NDS;
    const float* cr = cents + ((size_t)c * NK + bk) * NDS;
    float ex = dot16(xr, cr);                 // exact f32 value for the winner
    size_t o = (size_t)b * NC + c;
    negout[o] = -ex;
    codefout[o] = (float)bk;
    codeint[o] = bk;
    flags[o] = (best - sec > CERT) ? 0 : 1;   // uncertified -> phase B
  }
}

// ---------------------------------------------------------------------------
// Phase B: exact f32 rescue of uncertified entries. One wave cooperates per
// entry: lane handles k = lane*4..lane*4+3 (ascending => first-index ties),
// butterfly reduce with (greater) or (equal && smaller k).
// ---------------------------------------------------------------------------
__global__ __launch_bounds__(256) void k_phaseB(const float* __restrict__ inputs,
                                                const float* __restrict__ cents,
                                                const unsigned char* __restrict__ flags,
                                                float* __restrict__ negout,
                                                float* __restrict__ codefout,
                                                int* __restrict__ codeint) {
  const int l = threadIdx.x & 63;
  const int wid = (blockIdx.x * 256 + threadIdx.x) >> 6;   // 0..4095
#pragma unroll 1
  for (int chunk = 0; chunk < 4; ++chunk) {
    const int e0 = wid * 256 + chunk * 64;
    unsigned char f = flags[e0 + l];
    unsigned long long mask = __ballot(f != 0);
    while (mask) {
      const int j = __builtin_ctzll(mask);
      mask &= mask - 1;
      const int e = e0 + j;
      const int c = e & (NC - 1);
      const float* xr = inputs + (size_t)e * NDS;          // e == b*NC + c
      const float* cr = cents + ((size_t)c * NK + l * 4) * NDS;
      float best = -3.0e38f;
      int bk = 0;
#pragma unroll
      for (int q = 0; q < 4; ++q) {
        float d = dot16(xr, cr + q * NDS);
        if (d > best) { best = d; bk = l * 4 + q; }        // strict >, ascending k
      }
#pragma unroll
      for (int off = 1; off <= 32; off <<= 1) {
        float vb = __shfl_xor(best, off);
        int kb = __shfl_xor(bk, off);
        bool take = (vb > best) || (vb == best && kb < bk);
        best = take ? vb : best;
        bk = take ? kb : bk;
      }
      if (l == 0) {
        negout[e] = -best;
        codefout[e] = (float)bk;
        codeint[e] = bk;
      }
    }
  }
}

// ---------------------------------------------------------------------------
// Kernel 2: product = gather(centsH, codes) @ W   via bf16 MFMA  (unchanged)
// ---------------------------------------------------------------------------
__global__ __launch_bounds__(256) void k_gemm(const unsigned short* __restrict__ centsB,
                                              const int* __restrict__ codeint,
                                              const unsigned short* __restrict__ Wt,
                                              float* __restrict__ out) {
  __shared__ __align__(16) unsigned short As[128 * 64];
  __shared__ __align__(16) unsigned short Bs[128 * 64];
  __shared__ int lcode[128 * 33];

  const int t = threadIdx.x;
  const int l = t & 63;
  const int w = t >> 6;
  const int wm = w >> 1, wn = w & 1;
  const int m0 = blockIdx.x * 128;
  const int n0 = blockIdx.y * 128;

  {
    const int4* cp = (const int4*)(codeint + (size_t)m0 * NC);
#pragma unroll
    for (int i = 0; i < 4; ++i) {
      int idx = t + i * 256;
      int4 v = cp[idx];
      int row = idx >> 3, col = (idx & 7) * 4;
      lcode[row * 33 + col + 0] = v.x;
      lcode[row * 33 + col + 1] = v.y;
      lcode[row * 33 + col + 2] = v.z;
      lcode[row * 33 + col + 3] = v.w;
    }
  }

  f4v acc[4][4] = {};
  const int s = t & 7;
  const int rq = t >> 3;

  for (int kt = 0; kt < 8; ++kt) {
    __syncthreads();
    const int c0 = kt * 4;
#pragma unroll
    for (int i = 0; i < 4; ++i) {
      int lr = i * 32 + rq;
      int srcslot = s ^ (lr & 7);
      int cl = srcslot >> 1, half = srcslot & 1;
      int code = lcode[lr * 33 + c0 + cl];
      const unsigned short* gsrc =
          centsB + ((size_t)((c0 + cl) * NK + code) * NDS + half * 8);
      gload16(gsrc, (char*)As + i * 4096 + (w << 10));
    }
#pragma unroll
    for (int i = 0; i < 4; ++i) {
      int lr = i * 32 + rq;
      int k16 = s ^ (lr & 7);
      const unsigned short* gsrc = Wt + (size_t)(n0 + lr) * NDIN + kt * 64 + k16 * 8;
      gload16(gsrc, (char*)Bs + i * 4096 + (w << 10));
    }
    __syncthreads();

    s8v af[4][2], bfr[4][2];
#pragma unroll
    for (int mf = 0; mf < 4; ++mf)
#pragma unroll
      for (int ks = 0; ks < 2; ++ks) {
        int row = wm * 64 + mf * 16 + (l & 15);
        int slot = ks * 4 + (l >> 4);
        af[mf][ks] = *(const s8v*)((const char*)As + row * 128 + ((slot ^ (row & 7)) << 4));
      }
#pragma unroll
    for (int nf = 0; nf < 4; ++nf)
#pragma unroll
      for (int ks = 0; ks < 2; ++ks) {
        int row = wn * 64 + nf * 16 + (l & 15);
        int slot = ks * 4 + (l >> 4);
        bfr[nf][ks] = *(const s8v*)((const char*)Bs + row * 128 + ((slot ^ (row & 7)) << 4));
      }
#pragma unroll
    for (int ks = 0; ks < 2; ++ks)
#pragma unroll
      for (int mf = 0; mf < 4; ++mf)
#pragma unroll
        for (int nf = 0; nf < 4; ++nf)
          acc[mf][nf] = __builtin_amdgcn_mfma_f32_16x16x32_bf16(
              af[mf][ks], bfr[nf][ks], acc[mf][nf], 0, 0, 0);
  }

#pragma unroll
  for (int mf = 0; mf < 4; ++mf)
#pragma unroll
    for (int nf = 0; nf < 4; ++nf)
#pragma unroll
      for (int r = 0; r < 4; ++r) {
        int row = m0 + wm * 64 + mf * 16 + (l >> 4) * 4 + r;
        int col = n0 + wn * 64 + nf * 16 + (l & 15);
        out[(size_t)row * NDOUT + col] = acc[mf][nf][r];
      }
}

// ---------------------------------------------------------------------------
extern "C" void kernel_launch(void* const* d_in, const int* in_sizes, int n_in,
                              void* d_out, int out_size, void* d_ws, size_t ws_size,
                              hipStream_t stream) {
  const float* inputs = (const float*)d_in[0];   // (B, C, 16) f32
  const float* cents  = (const float*)d_in[1];   // (C, K, 16) f32
  const float* W      = (const float*)d_in[2];   // (512, 512) f32

  float* out = (float*)d_out;
  float* negout   = out + (size_t)NB * NDOUT;            // (B, C)
  float* codefout = negout + (size_t)NB * NC;            // (B, C) as float

  unsigned short* Wt     = (unsigned short*)d_ws;                          // 512 KiB
  unsigned short* centsH = (unsigned short*)((char*)d_ws + 512 * 1024);    // 256 KiB
  unsigned short* centsL = (unsigned short*)((char*)d_ws + 768 * 1024);    // 256 KiB
  int* codeint           = (int*)((char*)d_ws + (1 << 20));                // 4 MiB
  unsigned char* flags   = (unsigned char*)((char*)d_ws + 5 * (1 << 20));  // 1 MiB

  k_prep<<<288, 256, 0, stream>>>(W, cents, Wt, centsH, centsL);
  k_phaseA<<<dim3(NB / 128, NC), 256, 0, stream>>>(inputs, centsH, centsL, cents,
                                                   negout, codefout, codeint, flags);
  k_phaseB<<<1024, 256, 0, stream>>>(inputs, cents, flags, negout, codefout, codeint);
  k_gemm<<<dim3(NB / 128, NDOUT / 128), 256, 0, stream>>>(centsH, codeint, Wt, out);
}

// Round 8
// 203.948 us; speedup vs baseline: 1.0002x; 1.0002x over previous
//
#include <hip/hip_runtime.h>

// DPQ network:
//  k_score : response argmax via split-bf16 MFMA (ah*bh + al*bh + ah*bl),
//            certification margin, exact f32 dot for winner; outputs in
//            TRANSPOSED [c][b] layout (coalesced, XCD-private lines)
//  k_finish: tile-transpose [c][b] -> [b][c] + in-LDS exact rescue of
//            uncertified entries (first-index tie, matches np.argmax)
//  k_gemm  : codebook-gather GEMM (bf16 MFMA), unchanged from passing rounds
// B=32768, C=32, K=256, D_SUB=16, D_IN=512, D_OUT=512

#define NB 32768
#define NC 32
#define NK 256
#define NDS 16
#define NDIN 512
#define NDOUT 512
#define CERT 0.05f

typedef __attribute__((ext_vector_type(8))) short s8v;   // 8 bf16 in 4 VGPRs
typedef __attribute__((ext_vector_type(4))) float f4v;   // MFMA accumulator

__device__ __forceinline__ unsigned short f2bf(float f) {
  unsigned int u = __float_as_uint(f);
  u += 0x7fffu + ((u >> 16) & 1u);   // RNE
  return (unsigned short)(u >> 16);
}
__device__ __forceinline__ float bf2f(unsigned short h) {
  return __uint_as_float(((unsigned int)h) << 16);
}

__device__ __forceinline__ void gload16(const void* g, void* l) {
  __builtin_amdgcn_global_load_lds(
      (const __attribute__((address_space(1))) void*)g,
      (__attribute__((address_space(3))) void*)l, 16, 0, 0);
}

// exact f32 dot over 16 dims, sequential fold (same association everywhere)
__device__ __forceinline__ float dot16(const float* x, const float* cj) {
  float4 a0 = *(const float4*)(x + 0),  a1 = *(const float4*)(x + 4);
  float4 a2 = *(const float4*)(x + 8),  a3 = *(const float4*)(x + 12);
  float4 c0 = *(const float4*)(cj + 0), c1 = *(const float4*)(cj + 4);
  float4 c2 = *(const float4*)(cj + 8), c3 = *(const float4*)(cj + 12);
  float s = a0.x * c0.x;
  s = fmaf(a0.y, c0.y, s); s = fmaf(a0.z, c0.z, s); s = fmaf(a0.w, c0.w, s);
  s = fmaf(a1.x, c1.x, s); s = fmaf(a1.y, c1.y, s); s = fmaf(a1.z, c1.z, s); s = fmaf(a1.w, c1.w, s);
  s = fmaf(a2.x, c2.x, s); s = fmaf(a2.y, c2.y, s); s = fmaf(a2.z, c2.z, s); s = fmaf(a2.w, c2.w, s);
  s = fmaf(a3.x, c3.x, s); s = fmaf(a3.y, c3.y, s); s = fmaf(a3.z, c3.z, s); s = fmaf(a3.w, c3.w, s);
  return s;
}

// ---------------------------------------------------------------------------
// Kernel 0: Wt[n][k] = bf16(W[k][n]); centsH/centsL = bf16 hi/lo split of cents
// ---------------------------------------------------------------------------
__global__ __launch_bounds__(256) void k_prep(const float* __restrict__ W,
                                              const float* __restrict__ cents,
                                              unsigned short* __restrict__ Wt,
                                              unsigned short* __restrict__ centsH,
                                              unsigned short* __restrict__ centsL) {
  const int t = threadIdx.x;
  const int bid = blockIdx.x;
  if (bid < 256) {
    __shared__ float tile[32][33];
    const int k0 = (bid >> 4) << 5;
    const int n0 = (bid & 15) << 5;
    const int tx = t & 31, ty = t >> 5;
#pragma unroll
    for (int i = 0; i < 4; ++i) {
      int r = ty + i * 8;
      tile[r][tx] = W[(size_t)(k0 + r) * NDOUT + n0 + tx];
    }
    __syncthreads();
#pragma unroll
    for (int i = 0; i < 4; ++i) {
      int r = ty + i * 8;
      Wt[(size_t)(n0 + r) * NDIN + k0 + tx] = f2bf(tile[tx][r]);
    }
  } else {
    // hi/lo split of centroids: 131072 floats, blocks 256..287
    const int i0 = (bid - 256) * 4096 + t * 16;
#pragma unroll
    for (int j = 0; j < 4; ++j) {
      float4 v = *(const float4*)(cents + i0 + j * 4);
      unsigned short h0 = f2bf(v.x), h1 = f2bf(v.y), h2 = f2bf(v.z), h3 = f2bf(v.w);
      unsigned short l0 = f2bf(v.x - bf2f(h0)), l1 = f2bf(v.y - bf2f(h1));
      unsigned short l2 = f2bf(v.z - bf2f(h2)), l3 = f2bf(v.w - bf2f(h3));
      *(ushort4*)(centsH + i0 + j * 4) = make_ushort4(h0, h1, h2, h3);
      *(ushort4*)(centsL + i0 + j * 4) = make_ushort4(l0, l1, l2, l3);
    }
  }
}

// ---------------------------------------------------------------------------
// k_score: per wave = 32 b's x 1 c (MFMA core identical to the passing R7
// phaseA). Output: T_neg[c][b] = exact f32 max (raw), T_code[c][b] =
// bk | (uncertified ? 256 : 0). Contiguous 128B stores per wave.
// ---------------------------------------------------------------------------
__global__ __launch_bounds__(256) void k_score(const float* __restrict__ inputs,
                                               const unsigned short* __restrict__ centsH,
                                               const unsigned short* __restrict__ centsL,
                                               const float* __restrict__ cents,
                                               float* __restrict__ T_neg,
                                               int* __restrict__ T_code) {
  const int t = threadIdx.x;
  const int l = t & 63;
  const int w = t >> 6;
  const int c = blockIdx.y;
  const int b0 = blockIdx.x * 128 + w * 32;   // this wave: b0..b0+31 (two 16-col subtiles)
  const int g = l >> 4;
  const int col = l & 15;
  const int dh = (g & 1) * 8;                 // d-range this lane covers (contraction slots)
  const int g4 = g * 4;                       // k-row offset of this lane's C rows

  // ---- B fragments (two subtiles), hi/lo split in-register
  s8v bh0, bl0, bh1, bl1;
  {
    const float* r0 = inputs + ((size_t)(b0 + col) * NC + c) * NDS + dh;
    const float* r1 = inputs + ((size_t)(b0 + 16 + col) * NC + c) * NDS + dh;
    float4 u0 = *(const float4*)(r0), u1 = *(const float4*)(r0 + 4);
    float4 v0 = *(const float4*)(r1), v1 = *(const float4*)(r1 + 4);
    unsigned short h0 = f2bf(u0.x), h1 = f2bf(u0.y), h2 = f2bf(u0.z), h3 = f2bf(u0.w);
    unsigned short h4 = f2bf(u1.x), h5 = f2bf(u1.y), h6 = f2bf(u1.z), h7 = f2bf(u1.w);
    bh0 = s8v{(short)h0, (short)h1, (short)h2, (short)h3,
              (short)h4, (short)h5, (short)h6, (short)h7};
    bl0 = s8v{(short)f2bf(u0.x - bf2f(h0)), (short)f2bf(u0.y - bf2f(h1)),
              (short)f2bf(u0.z - bf2f(h2)), (short)f2bf(u0.w - bf2f(h3)),
              (short)f2bf(u1.x - bf2f(h4)), (short)f2bf(u1.y - bf2f(h5)),
              (short)f2bf(u1.z - bf2f(h6)), (short)f2bf(u1.w - bf2f(h7))};
    unsigned short j0 = f2bf(v0.x), j1 = f2bf(v0.y), j2 = f2bf(v0.z), j3 = f2bf(v0.w);
    unsigned short j4 = f2bf(v1.x), j5 = f2bf(v1.y), j6 = f2bf(v1.z), j7 = f2bf(v1.w);
    bh1 = s8v{(short)j0, (short)j1, (short)j2, (short)j3,
              (short)j4, (short)j5, (short)j6, (short)j7};
    bl1 = s8v{(short)f2bf(v0.x - bf2f(j0)), (short)f2bf(v0.y - bf2f(j1)),
              (short)f2bf(v0.z - bf2f(j2)), (short)f2bf(v0.w - bf2f(j3)),
              (short)f2bf(v1.x - bf2f(j4)), (short)f2bf(v1.y - bf2f(j5)),
              (short)f2bf(v1.z - bf2f(j6)), (short)f2bf(v1.w - bf2f(j7))};
    const s8v zer = {0, 0, 0, 0, 0, 0, 0, 0};
    if (l >= 32) { bl0 = zer; bl1 = zer; }    // kappa>=16 of pass-2 B is zero
  }

  // A-operand base: lanes g0,g1 -> hi; g2,g3 -> lo (kappa 16..31 = al)
  const unsigned short* ab =
      (l < 32 ? centsH : centsL) + ((size_t)c * NK + col) * NDS + dh;

  float best0 = -3.0e38f, sec0 = -3.0e38f;
  float best1 = -3.0e38f, sec1 = -3.0e38f;
  int bk0 = 0, bk1 = 0;
  const f4v zz = {0.0f, 0.0f, 0.0f, 0.0f};

#pragma unroll
  for (int kt = 0; kt < 16; ++kt) {
    s8v a = *(const s8v*)(ab + kt * 256);     // 16 k-rows per tile, 16 elems/row
    f4v acc0 = __builtin_amdgcn_mfma_f32_16x16x32_bf16(a, bh0, zz, 0, 0, 0);
    acc0 = __builtin_amdgcn_mfma_f32_16x16x32_bf16(a, bl0, acc0, 0, 0, 0);
    f4v acc1 = __builtin_amdgcn_mfma_f32_16x16x32_bf16(a, bh1, zz, 0, 0, 0);
    acc1 = __builtin_amdgcn_mfma_f32_16x16x32_bf16(a, bl1, acc1, 0, 0, 0);
#pragma unroll
    for (int r = 0; r < 4; ++r) {
      const int kc = kt * 16 + r;             // + g4 folded at the end
      float v = acc0[r];
      float mn = fminf(v, best0);
      sec0 = fmaxf(sec0, mn);
      bool gt = v > best0;
      bk0 = gt ? kc : bk0;
      best0 = fmaxf(best0, v);
      v = acc1[r];
      mn = fminf(v, best1);
      sec1 = fmaxf(sec1, mn);
      gt = v > best1;
      bk1 = gt ? kc : bk1;
      best1 = fmaxf(best1, v);
    }
  }
  bk0 += g4;
  bk1 += g4;

  // butterfly across the 4 lane-groups (same b-col at l, l^16, l^32, l^48)
#pragma unroll
  for (int off = 16; off <= 32; off <<= 1) {
    float vb = __shfl_xor(best0, off);
    float sb = __shfl_xor(sec0, off);
    int kb = __shfl_xor(bk0, off);
    float mn = fminf(best0, vb);
    sec0 = fmaxf(fmaxf(sec0, sb), mn);
    bool take = (vb > best0) || (vb == best0 && kb < bk0);
    bk0 = take ? kb : bk0;
    best0 = fmaxf(best0, vb);

    vb = __shfl_xor(best1, off);
    sb = __shfl_xor(sec1, off);
    kb = __shfl_xor(bk1, off);
    mn = fminf(best1, vb);
    sec1 = fmaxf(fmaxf(sec1, sb), mn);
    take = (vb > best1) || (vb == best1 && kb < bk1);
    bk1 = take ? kb : bk1;
    best1 = fmaxf(best1, vb);
  }

  // lanes 0..31 finalize b = b0 + l; transposed contiguous stores
  if (l < 32) {
    const int sub = l >> 4;
    float best = sub ? best1 : best0;
    float sec = sub ? sec1 : sec0;
    int bk = sub ? bk1 : bk0;
    const int b = b0 + l;
    const float* xr = inputs + ((size_t)b * NC + c) * NDS;
    const float* cr = cents + ((size_t)c * NK + bk) * NDS;
    float ex = dot16(xr, cr);                 // exact f32 value for the winner
    size_t o = (size_t)c * NB + b;
    T_neg[o] = ex;                            // raw max; negated in k_finish
    T_code[o] = bk | ((best - sec > CERT) ? 0 : 256);
  }
}

// ---------------------------------------------------------------------------
// k_finish: 64b x 32c tile per block. Coalesced load of T_neg/T_code along b,
// in-LDS exact rescue of flagged entries (wave-cooperative, lane k-split,
// first-index tie), then coalesced [b][c] stores of negout/codefout/codeint.
// ---------------------------------------------------------------------------
__global__ __launch_bounds__(256) void k_finish(const float* __restrict__ inputs,
                                                const float* __restrict__ cents,
                                                const float* __restrict__ T_neg,
                                                const int* __restrict__ T_code,
                                                float* __restrict__ negout,
                                                float* __restrict__ codefout,
                                                int* __restrict__ codeint) {
  __shared__ float sneg[64][33];
  __shared__ int scode[64][33];
  const int t = threadIdx.x;
  const int b0 = blockIdx.x * 64;

  // load (coalesced along b within each c)
#pragma unroll
  for (int it = 0; it < 8; ++it) {
    int lin = it * 256 + t;
    int c = lin >> 6, bi = lin & 63;
    sneg[bi][c] = T_neg[(size_t)c * NB + b0 + bi];
    scode[bi][c] = T_code[(size_t)c * NB + b0 + bi];
  }
  __syncthreads();

  // rescue flagged entries
  const int w = t >> 6, l = t & 63;
#pragma unroll 1
  for (int j = 0; j < 8; ++j) {
    int lin = w * 512 + j * 64 + l;
    int bi = lin >> 5, c = lin & 31;
    unsigned long long mask = __ballot((scode[bi][c] & 256) != 0);
    while (mask) {
      int p = __builtin_ctzll(mask);
      mask &= mask - 1;
      int lin2 = w * 512 + j * 64 + p;
      int bi2 = lin2 >> 5, c2 = lin2 & 31;
      const float* xr = inputs + ((size_t)(b0 + bi2) * NC + c2) * NDS;
      const float* cr = cents + ((size_t)c2 * NK + l * 4) * NDS;
      float best = -3.0e38f;
      int bk = 0;
#pragma unroll
      for (int q = 0; q < 4; ++q) {
        float d = dot16(xr, cr + q * NDS);
        if (d > best) { best = d; bk = l * 4 + q; }   // strict >, ascending k
      }
#pragma unroll
      for (int off = 1; off <= 32; off <<= 1) {
        float vb = __shfl_xor(best, off);
        int kb = __shfl_xor(bk, off);
        bool take = (vb > best) || (vb == best && kb < bk);
        best = take ? vb : best;
        bk = take ? kb : bk;
      }
      if (l == 0) { sneg[bi2][c2] = best; scode[bi2][c2] = bk; }
    }
  }
  __syncthreads();

  // store (coalesced along c within each b)
#pragma unroll
  for (int it = 0; it < 8; ++it) {
    int lin = it * 256 + t;
    int bi = lin >> 5, c = lin & 31;
    size_t o = (size_t)(b0 + bi) * NC + c;
    int code = scode[bi][c] & 0xFF;
    negout[o] = -sneg[bi][c];
    codefout[o] = (float)code;
    codeint[o] = code;
  }
}

// ---------------------------------------------------------------------------
// Kernel 2: product = gather(centsH, codes) @ W   via bf16 MFMA  (unchanged)
// ---------------------------------------------------------------------------
__global__ __launch_bounds__(256) void k_gemm(const unsigned short* __restrict__ centsB,
                                              const int* __restrict__ codeint,
                                              const unsigned short* __restrict__ Wt,
                                              float* __restrict__ out) {
  __shared__ __align__(16) unsigned short As[128 * 64];
  __shared__ __align__(16) unsigned short Bs[128 * 64];
  __shared__ int lcode[128 * 33];

  const int t = threadIdx.x;
  const int l = t & 63;
  const int w = t >> 6;
  const int wm = w >> 1, wn = w & 1;
  const int m0 = blockIdx.x * 128;
  const int n0 = blockIdx.y * 128;

  {
    const int4* cp = (const int4*)(codeint + (size_t)m0 * NC);
#pragma unroll
    for (int i = 0; i < 4; ++i) {
      int idx = t + i * 256;
      int4 v = cp[idx];
      int row = idx >> 3, col = (idx & 7) * 4;
      lcode[row * 33 + col + 0] = v.x;
      lcode[row * 33 + col + 1] = v.y;
      lcode[row * 33 + col + 2] = v.z;
      lcode[row * 33 + col + 3] = v.w;
    }
  }

  f4v acc[4][4] = {};
  const int s = t & 7;
  const int rq = t >> 3;

  for (int kt = 0; kt < 8; ++kt) {
    __syncthreads();
    const int c0 = kt * 4;
#pragma unroll
    for (int i = 0; i < 4; ++i) {
      int lr = i * 32 + rq;
      int srcslot = s ^ (lr & 7);
      int cl = srcslot >> 1, half = srcslot & 1;
      int code = lcode[lr * 33 + c0 + cl];
      const unsigned short* gsrc =
          centsB + ((size_t)((c0 + cl) * NK + code) * NDS + half * 8);
      gload16(gsrc, (char*)As + i * 4096 + (w << 10));
    }
#pragma unroll
    for (int i = 0; i < 4; ++i) {
      int lr = i * 32 + rq;
      int k16 = s ^ (lr & 7);
      const unsigned short* gsrc = Wt + (size_t)(n0 + lr) * NDIN + kt * 64 + k16 * 8;
      gload16(gsrc, (char*)Bs + i * 4096 + (w << 10));
    }
    __syncthreads();

    s8v af[4][2], bfr[4][2];
#pragma unroll
    for (int mf = 0; mf < 4; ++mf)
#pragma unroll
      for (int ks = 0; ks < 2; ++ks) {
        int row = wm * 64 + mf * 16 + (l & 15);
        int slot = ks * 4 + (l >> 4);
        af[mf][ks] = *(const s8v*)((const char*)As + row * 128 + ((slot ^ (row & 7)) << 4));
      }
#pragma unroll
    for (int nf = 0; nf < 4; ++nf)
#pragma unroll
      for (int ks = 0; ks < 2; ++ks) {
        int row = wn * 64 + nf * 16 + (l & 15);
        int slot = ks * 4 + (l >> 4);
        bfr[nf][ks] = *(const s8v*)((const char*)Bs + row * 128 + ((slot ^ (row & 7)) << 4));
      }
#pragma unroll
    for (int ks = 0; ks < 2; ++ks)
#pragma unroll
      for (int mf = 0; mf < 4; ++mf)
#pragma unroll
        for (int nf = 0; nf < 4; ++nf)
          acc[mf][nf] = __builtin_amdgcn_mfma_f32_16x16x32_bf16(
              af[mf][ks], bfr[nf][ks], acc[mf][nf], 0, 0, 0);
  }

#pragma unroll
  for (int mf = 0; mf < 4; ++mf)
#pragma unroll
    for (int nf = 0; nf < 4; ++nf)
#pragma unroll
      for (int r = 0; r < 4; ++r) {
        int row = m0 + wm * 64 + mf * 16 + (l >> 4) * 4 + r;
        int col = n0 + wn * 64 + nf * 16 + (l & 15);
        out[(size_t)row * NDOUT + col] = acc[mf][nf][r];
      }
}

// ---------------------------------------------------------------------------
extern "C" void kernel_launch(void* const* d_in, const int* in_sizes, int n_in,
                              void* d_out, int out_size, void* d_ws, size_t ws_size,
                              hipStream_t stream) {
  const float* inputs = (const float*)d_in[0];   // (B, C, 16) f32
  const float* cents  = (const float*)d_in[1];   // (C, K, 16) f32
  const float* W      = (const float*)d_in[2];   // (512, 512) f32

  float* out = (float*)d_out;
  float* negout   = out + (size_t)NB * NDOUT;            // (B, C)
  float* codefout = negout + (size_t)NB * NC;            // (B, C) as float

  unsigned short* Wt     = (unsigned short*)d_ws;                          // 512 KiB
  unsigned short* centsH = (unsigned short*)((char*)d_ws + 512 * 1024);    // 256 KiB
  unsigned short* centsL = (unsigned short*)((char*)d_ws + 768 * 1024);    // 256 KiB
  int* codeint           = (int*)((char*)d_ws + (1 << 20));                // 4 MiB
  float* T_neg           = (float*)((char*)d_ws + 5 * (1 << 20));          // 4 MiB
  int* T_code            = (int*)((char*)d_ws + 9 * (1 << 20));            // 4 MiB

  k_prep<<<288, 256, 0, stream>>>(W, cents, Wt, centsH, centsL);
  k_score<<<dim3(NB / 128, NC), 256, 0, stream>>>(inputs, centsH, centsL, cents,
                                                  T_neg, T_code);
  k_finish<<<NB / 64, 256, 0, stream>>>(inputs, cents, T_neg, T_code,
                                        negout, codefout, codeint);
  k_gemm<<<dim3(NB / 128, NDOUT / 128), 256, 0, stream>>>(centsH, codeint, Wt, out);
}

// Round 9
// 135.870 us; speedup vs baseline: 1.5014x; 1.5011x over previous
//
#include <hip/hip_runtime.h>

// DPQ network:
//  k_score : response argmax via split-bf16 MFMA (ah*bh + al*bh + ah*bl),
//            certification margin + INLINE exact-f32 rescue (latency hidden
//            by 74% occupancy); outputs TRANSPOSED [c][b] (coalesced stores)
//  k_finish: pure tile-transpose [c][b] -> [b][c] (both sides coalesced)
//  k_gemm  : codebook-gather GEMM (bf16 MFMA), unchanged from passing rounds
// B=32768, C=32, K=256, D_SUB=16, D_IN=512, D_OUT=512

#define NB 32768
#define NC 32
#define NK 256
#define NDS 16
#define NDIN 512
#define NDOUT 512
#define CERT 0.02f

typedef __attribute__((ext_vector_type(8))) short s8v;   // 8 bf16 in 4 VGPRs
typedef __attribute__((ext_vector_type(4))) float f4v;   // MFMA accumulator

__device__ __forceinline__ unsigned short f2bf(float f) {
  unsigned int u = __float_as_uint(f);
  u += 0x7fffu + ((u >> 16) & 1u);   // RNE
  return (unsigned short)(u >> 16);
}
__device__ __forceinline__ float bf2f(unsigned short h) {
  return __uint_as_float(((unsigned int)h) << 16);
}

__device__ __forceinline__ void gload16(const void* g, void* l) {
  __builtin_amdgcn_global_load_lds(
      (const __attribute__((address_space(1))) void*)g,
      (__attribute__((address_space(3))) void*)l, 16, 0, 0);
}

// exact f32 dot over 16 dims, sequential fold (same association everywhere)
__device__ __forceinline__ float dot16(const float* x, const float* cj) {
  float4 a0 = *(const float4*)(x + 0),  a1 = *(const float4*)(x + 4);
  float4 a2 = *(const float4*)(x + 8),  a3 = *(const float4*)(x + 12);
  float4 c0 = *(const float4*)(cj + 0), c1 = *(const float4*)(cj + 4);
  float4 c2 = *(const float4*)(cj + 8), c3 = *(const float4*)(cj + 12);
  float s = a0.x * c0.x;
  s = fmaf(a0.y, c0.y, s); s = fmaf(a0.z, c0.z, s); s = fmaf(a0.w, c0.w, s);
  s = fmaf(a1.x, c1.x, s); s = fmaf(a1.y, c1.y, s); s = fmaf(a1.z, c1.z, s); s = fmaf(a1.w, c1.w, s);
  s = fmaf(a2.x, c2.x, s); s = fmaf(a2.y, c2.y, s); s = fmaf(a2.z, c2.z, s); s = fmaf(a2.w, c2.w, s);
  s = fmaf(a3.x, c3.x, s); s = fmaf(a3.y, c3.y, s); s = fmaf(a3.z, c3.z, s); s = fmaf(a3.w, c3.w, s);
  return s;
}

// ---------------------------------------------------------------------------
// Kernel 0: Wt[n][k] = bf16(W[k][n]); centsH/centsL = bf16 hi/lo split of cents
// ---------------------------------------------------------------------------
__global__ __launch_bounds__(256) void k_prep(const float* __restrict__ W,
                                              const float* __restrict__ cents,
                                              unsigned short* __restrict__ Wt,
                                              unsigned short* __restrict__ centsH,
                                              unsigned short* __restrict__ centsL) {
  const int t = threadIdx.x;
  const int bid = blockIdx.x;
  if (bid < 256) {
    __shared__ float tile[32][33];
    const int k0 = (bid >> 4) << 5;
    const int n0 = (bid & 15) << 5;
    const int tx = t & 31, ty = t >> 5;
#pragma unroll
    for (int i = 0; i < 4; ++i) {
      int r = ty + i * 8;
      tile[r][tx] = W[(size_t)(k0 + r) * NDOUT + n0 + tx];
    }
    __syncthreads();
#pragma unroll
    for (int i = 0; i < 4; ++i) {
      int r = ty + i * 8;
      Wt[(size_t)(n0 + r) * NDIN + k0 + tx] = f2bf(tile[tx][r]);
    }
  } else {
    // hi/lo split of centroids: 131072 floats, blocks 256..287
    const int i0 = (bid - 256) * 4096 + t * 16;
#pragma unroll
    for (int j = 0; j < 4; ++j) {
      float4 v = *(const float4*)(cents + i0 + j * 4);
      unsigned short h0 = f2bf(v.x), h1 = f2bf(v.y), h2 = f2bf(v.z), h3 = f2bf(v.w);
      unsigned short l0 = f2bf(v.x - bf2f(h0)), l1 = f2bf(v.y - bf2f(h1));
      unsigned short l2 = f2bf(v.z - bf2f(h2)), l3 = f2bf(v.w - bf2f(h3));
      *(ushort4*)(centsH + i0 + j * 4) = make_ushort4(h0, h1, h2, h3);
      *(ushort4*)(centsL + i0 + j * 4) = make_ushort4(l0, l1, l2, l3);
    }
  }
}

// ---------------------------------------------------------------------------
// k_score: per wave = 32 b's x 1 c. MFMA core + certification identical to
// the passing R8 kernel. Uncertified entries are rescued INLINE (whole-wave
// exact-f32 rescan, ballot-serialized, latency hidden by occupancy).
// Output: T_neg[c][b] = exact f32 max, T_code[c][b] = final code.
// ---------------------------------------------------------------------------
__global__ __launch_bounds__(256) void k_score(const float* __restrict__ inputs,
                                               const unsigned short* __restrict__ centsH,
                                               const unsigned short* __restrict__ centsL,
                                               const float* __restrict__ cents,
                                               float* __restrict__ T_neg,
                                               int* __restrict__ T_code) {
  const int t = threadIdx.x;
  const int l = t & 63;
  const int w = t >> 6;
  const int c = blockIdx.y;
  const int b0 = blockIdx.x * 128 + w * 32;   // this wave: b0..b0+31 (two 16-col subtiles)
  const int g = l >> 4;
  const int col = l & 15;
  const int dh = (g & 1) * 8;                 // d-range this lane covers (contraction slots)
  const int g4 = g * 4;                       // k-row offset of this lane's C rows

  // ---- B fragments (two subtiles), hi/lo split in-register
  s8v bh0, bl0, bh1, bl1;
  {
    const float* r0 = inputs + ((size_t)(b0 + col) * NC + c) * NDS + dh;
    const float* r1 = inputs + ((size_t)(b0 + 16 + col) * NC + c) * NDS + dh;
    float4 u0 = *(const float4*)(r0), u1 = *(const float4*)(r0 + 4);
    float4 v0 = *(const float4*)(r1), v1 = *(const float4*)(r1 + 4);
    unsigned short h0 = f2bf(u0.x), h1 = f2bf(u0.y), h2 = f2bf(u0.z), h3 = f2bf(u0.w);
    unsigned short h4 = f2bf(u1.x), h5 = f2bf(u1.y), h6 = f2bf(u1.z), h7 = f2bf(u1.w);
    bh0 = s8v{(short)h0, (short)h1, (short)h2, (short)h3,
              (short)h4, (short)h5, (short)h6, (short)h7};
    bl0 = s8v{(short)f2bf(u0.x - bf2f(h0)), (short)f2bf(u0.y - bf2f(h1)),
              (short)f2bf(u0.z - bf2f(h2)), (short)f2bf(u0.w - bf2f(h3)),
              (short)f2bf(u1.x - bf2f(h4)), (short)f2bf(u1.y - bf2f(h5)),
              (short)f2bf(u1.z - bf2f(h6)), (short)f2bf(u1.w - bf2f(h7))};
    unsigned short j0 = f2bf(v0.x), j1 = f2bf(v0.y), j2 = f2bf(v0.z), j3 = f2bf(v0.w);
    unsigned short j4 = f2bf(v1.x), j5 = f2bf(v1.y), j6 = f2bf(v1.z), j7 = f2bf(v1.w);
    bh1 = s8v{(short)j0, (short)j1, (short)j2, (short)j3,
              (short)j4, (short)j5, (short)j6, (short)j7};
    bl1 = s8v{(short)f2bf(v0.x - bf2f(j0)), (short)f2bf(v0.y - bf2f(j1)),
              (short)f2bf(v0.z - bf2f(j2)), (short)f2bf(v0.w - bf2f(j3)),
              (short)f2bf(v1.x - bf2f(j4)), (short)f2bf(v1.y - bf2f(j5)),
              (short)f2bf(v1.z - bf2f(j6)), (short)f2bf(v1.w - bf2f(j7))};
    const s8v zer = {0, 0, 0, 0, 0, 0, 0, 0};
    if (l >= 32) { bl0 = zer; bl1 = zer; }    // kappa>=16 of pass-2 B is zero
  }

  // A-operand base: lanes g0,g1 -> hi; g2,g3 -> lo (kappa 16..31 = al)
  const unsigned short* ab =
      (l < 32 ? centsH : centsL) + ((size_t)c * NK + col) * NDS + dh;

  float best0 = -3.0e38f, sec0 = -3.0e38f;
  float best1 = -3.0e38f, sec1 = -3.0e38f;
  int bk0 = 0, bk1 = 0;
  const f4v zz = {0.0f, 0.0f, 0.0f, 0.0f};

#pragma unroll
  for (int kt = 0; kt < 16; ++kt) {
    s8v a = *(const s8v*)(ab + kt * 256);     // 16 k-rows per tile, 16 elems/row
    f4v acc0 = __builtin_amdgcn_mfma_f32_16x16x32_bf16(a, bh0, zz, 0, 0, 0);
    acc0 = __builtin_amdgcn_mfma_f32_16x16x32_bf16(a, bl0, acc0, 0, 0, 0);
    f4v acc1 = __builtin_amdgcn_mfma_f32_16x16x32_bf16(a, bh1, zz, 0, 0, 0);
    acc1 = __builtin_amdgcn_mfma_f32_16x16x32_bf16(a, bl1, acc1, 0, 0, 0);
#pragma unroll
    for (int r = 0; r < 4; ++r) {
      const int kc = kt * 16 + r;             // + g4 folded at the end
      float v = acc0[r];
      float mn = fminf(v, best0);
      sec0 = fmaxf(sec0, mn);
      bool gt = v > best0;
      bk0 = gt ? kc : bk0;
      best0 = fmaxf(best0, v);
      v = acc1[r];
      mn = fminf(v, best1);
      sec1 = fmaxf(sec1, mn);
      gt = v > best1;
      bk1 = gt ? kc : bk1;
      best1 = fmaxf(best1, v);
    }
  }
  bk0 += g4;
  bk1 += g4;

  // butterfly across the 4 lane-groups (same b-col at l, l^16, l^32, l^48)
#pragma unroll
  for (int off = 16; off <= 32; off <<= 1) {
    float vb = __shfl_xor(best0, off);
    float sb = __shfl_xor(sec0, off);
    int kb = __shfl_xor(bk0, off);
    float mn = fminf(best0, vb);
    sec0 = fmaxf(fmaxf(sec0, sb), mn);
    bool take = (vb > best0) || (vb == best0 && kb < bk0);
    bk0 = take ? kb : bk0;
    best0 = fmaxf(best0, vb);

    vb = __shfl_xor(best1, off);
    sb = __shfl_xor(sec1, off);
    kb = __shfl_xor(bk1, off);
    mn = fminf(best1, vb);
    sec1 = fmaxf(fmaxf(sec1, sb), mn);
    take = (vb > best1) || (vb == best1 && kb < bk1);
    bk1 = take ? kb : bk1;
    best1 = fmaxf(best1, vb);
  }

  // per-result-lane final values (lanes 0..31 own b = b0 + l)
  const int sub = (l >> 4) & 1;
  float best = sub ? best1 : best0;
  float sec = sub ? sec1 : sec0;
  int bk = sub ? bk1 : bk0;
  const bool owner = (l < 32);
  const bool flagged = owner && (best - sec <= CERT);

  // certified entries: exact f32 value for the winner, store
  if (owner && !flagged) {
    const int b = b0 + l;
    const float* xr = inputs + ((size_t)b * NC + c) * NDS;
    const float* cr = cents + ((size_t)c * NK + bk) * NDS;
    size_t o = (size_t)c * NB + b;
    T_neg[o] = dot16(xr, cr);
    T_code[o] = bk;
  }

  // inline rescue: whole wave rescans flagged entries exactly (f32)
  unsigned long long mask = __ballot(flagged);
  while (mask) {
    const int p = __builtin_ctzll(mask);
    mask &= mask - 1;
    const int b = b0 + p;
    const float* xr = inputs + ((size_t)b * NC + c) * NDS;
    const float* cr = cents + ((size_t)c * NK + l * 4) * NDS;
    float rb = -3.0e38f;
    int rk = 0;
#pragma unroll
    for (int q = 0; q < 4; ++q) {
      float d = dot16(xr, cr + q * NDS);
      if (d > rb) { rb = d; rk = l * 4 + q; }   // strict >, ascending k
    }
#pragma unroll
    for (int off = 1; off <= 32; off <<= 1) {
      float vb = __shfl_xor(rb, off);
      int kb = __shfl_xor(rk, off);
      bool take = (vb > rb) || (vb == rb && kb < rk);
      rb = take ? vb : rb;
      rk = take ? kb : rk;
    }
    if (l == 0) {
      size_t o = (size_t)c * NB + b;
      T_neg[o] = rb;
      T_code[o] = rk;
    }
  }
}

// ---------------------------------------------------------------------------
// k_finish: pure transpose. 64b x 32c tile per block; coalesced loads along b,
// coalesced [b][c] stores of negout/codefout/codeint.
// ---------------------------------------------------------------------------
__global__ __launch_bounds__(256) void k_finish(const float* __restrict__ T_neg,
                                                const int* __restrict__ T_code,
                                                float* __restrict__ negout,
                                                float* __restrict__ codefout,
                                                int* __restrict__ codeint) {
  __shared__ float sneg[64][33];
  __shared__ int scode[64][33];
  const int t = threadIdx.x;
  const int b0 = blockIdx.x * 64;

  // load (coalesced along b within each c)
#pragma unroll
  for (int it = 0; it < 8; ++it) {
    int lin = it * 256 + t;
    int c = lin >> 6, bi = lin & 63;
    sneg[bi][c] = T_neg[(size_t)c * NB + b0 + bi];
    scode[bi][c] = T_code[(size_t)c * NB + b0 + bi];
  }
  __syncthreads();

  // store (coalesced along c within each b)
#pragma unroll
  for (int it = 0; it < 8; ++it) {
    int lin = it * 256 + t;
    int bi = lin >> 5, c = lin & 31;
    size_t o = (size_t)(b0 + bi) * NC + c;
    int code = scode[bi][c];
    negout[o] = -sneg[bi][c];
    codefout[o] = (float)code;
    codeint[o] = code;
  }
}

// ---------------------------------------------------------------------------
// Kernel 2: product = gather(centsH, codes) @ W   via bf16 MFMA  (unchanged)
// ---------------------------------------------------------------------------
__global__ __launch_bounds__(256) void k_gemm(const unsigned short* __restrict__ centsB,
                                              const int* __restrict__ codeint,
                                              const unsigned short* __restrict__ Wt,
                                              float* __restrict__ out) {
  __shared__ __align__(16) unsigned short As[128 * 64];
  __shared__ __align__(16) unsigned short Bs[128 * 64];
  __shared__ int lcode[128 * 33];

  const int t = threadIdx.x;
  const int l = t & 63;
  const int w = t >> 6;
  const int wm = w >> 1, wn = w & 1;
  const int m0 = blockIdx.x * 128;
  const int n0 = blockIdx.y * 128;

  {
    const int4* cp = (const int4*)(codeint + (size_t)m0 * NC);
#pragma unroll
    for (int i = 0; i < 4; ++i) {
      int idx = t + i * 256;
      int4 v = cp[idx];
      int row = idx >> 3, col = (idx & 7) * 4;
      lcode[row * 33 + col + 0] = v.x;
      lcode[row * 33 + col + 1] = v.y;
      lcode[row * 33 + col + 2] = v.z;
      lcode[row * 33 + col + 3] = v.w;
    }
  }

  f4v acc[4][4] = {};
  const int s = t & 7;
  const int rq = t >> 3;

  for (int kt = 0; kt < 8; ++kt) {
    __syncthreads();
    const int c0 = kt * 4;
#pragma unroll
    for (int i = 0; i < 4; ++i) {
      int lr = i * 32 + rq;
      int srcslot = s ^ (lr & 7);
      int cl = srcslot >> 1, half = srcslot & 1;
      int code = lcode[lr * 33 + c0 + cl];
      const unsigned short* gsrc =
          centsB + ((size_t)((c0 + cl) * NK + code) * NDS + half * 8);
      gload16(gsrc, (char*)As + i * 4096 + (w << 10));
    }
#pragma unroll
    for (int i = 0; i < 4; ++i) {
      int lr = i * 32 + rq;
      int k16 = s ^ (lr & 7);
      const unsigned short* gsrc = Wt + (size_t)(n0 + lr) * NDIN + kt * 64 + k16 * 8;
      gload16(gsrc, (char*)Bs + i * 4096 + (w << 10));
    }
    __syncthreads();

    s8v af[4][2], bfr[4][2];
#pragma unroll
    for (int mf = 0; mf < 4; ++mf)
#pragma unroll
      for (int ks = 0; ks < 2; ++ks) {
        int row = wm * 64 + mf * 16 + (l & 15);
        int slot = ks * 4 + (l >> 4);
        af[mf][ks] = *(const s8v*)((const char*)As + row * 128 + ((slot ^ (row & 7)) << 4));
      }
#pragma unroll
    for (int nf = 0; nf < 4; ++nf)
#pragma unroll
      for (int ks = 0; ks < 2; ++ks) {
        int row = wn * 64 + nf * 16 + (l & 15);
        int slot = ks * 4 + (l >> 4);
        bfr[nf][ks] = *(const s8v*)((const char*)Bs + row * 128 + ((slot ^ (row & 7)) << 4));
      }
#pragma unroll
    for (int ks = 0; ks < 2; ++ks)
#pragma unroll
      for (int mf = 0; mf < 4; ++mf)
#pragma unroll
        for (int nf = 0; nf < 4; ++nf)
          acc[mf][nf] = __builtin_amdgcn_mfma_f32_16x16x32_bf16(
              af[mf][ks], bfr[nf][ks], acc[mf][nf], 0, 0, 0);
  }

#pragma unroll
  for (int mf = 0; mf < 4; ++mf)
#pragma unroll
    for (int nf = 0; nf < 4; ++nf)
#pragma unroll
      for (int r = 0; r < 4; ++r) {
        int row = m0 + wm * 64 + mf * 16 + (l >> 4) * 4 + r;
        int col = n0 + wn * 64 + nf * 16 + (l & 15);
        out[(size_t)row * NDOUT + col] = acc[mf][nf][r];
      }
}

// ---------------------------------------------------------------------------
extern "C" void kernel_launch(void* const* d_in, const int* in_sizes, int n_in,
                              void* d_out, int out_size, void* d_ws, size_t ws_size,
                              hipStream_t stream) {
  const float* inputs = (const float*)d_in[0];   // (B, C, 16) f32
  const float* cents  = (const float*)d_in[1];   // (C, K, 16) f32
  const float* W      = (const float*)d_in[2];   // (512, 512) f32

  float* out = (float*)d_out;
  float* negout   = out + (size_t)NB * NDOUT;            // (B, C)
  float* codefout = negout + (size_t)NB * NC;            // (B, C) as float

  unsigned short* Wt     = (unsigned short*)d_ws;                          // 512 KiB
  unsigned short* centsH = (unsigned short*)((char*)d_ws + 512 * 1024);    // 256 KiB
  unsigned short* centsL = (unsigned short*)((char*)d_ws + 768 * 1024);    // 256 KiB
  int* codeint           = (int*)((char*)d_ws + (1 << 20));                // 4 MiB
  float* T_neg           = (float*)((char*)d_ws + 5 * (1 << 20));          // 4 MiB
  int* T_code            = (int*)((char*)d_ws + 9 * (1 << 20));            // 4 MiB

  k_prep<<<288, 256, 0, stream>>>(W, cents, Wt, centsH, centsL);
  k_score<<<dim3(NB / 128, NC), 256, 0, stream>>>(inputs, centsH, centsL, cents,
                                                  T_neg, T_code);
  k_finish<<<NB / 64, 256, 0, stream>>>(T_neg, T_code, negout, codefout, codeint);
  k_gemm<<<dim3(NB / 128, NDOUT / 128), 256, 0, stream>>>(centsH, codeint, Wt, out);
}